// Round 7
// baseline (548.650 us; speedup 1.0000x reference)
//
#include <hip/hip_runtime.h>
#include <stdint.h>

// B=4, T=4096, D=1024, M=1024.  I/O fp32.  Round 12 = round 11 resubmitted
// (round-6 bench was an infra failure: "container failed twice"; no verdict).
// 32x32x16 MFMA, B-fragment reads hoisted to q0 (bfa[4][2] in registers
// across the K-tile), staging schedule identical to the proven round-9
// kernel (q0:B1(kt+1) q1:A0(kt+2) q2:A1(kt+2) q3:B0(kt+2), vmcnt(6),
// vmcnt(0)@kt=14).  Round 10's bug (B re-read from BOFF(kt&1,·) every phase
// while q3 staged into the same buffer) is gone: last B-read of a buffer
// completes at q0's lgkmcnt(0), two barriers before the q3 stage issue.

#define R_ROWS 16384
#define DIM    1024
#define MDIM   1024
#define TSEQ   4096
#define NCHUNK 128
#define TCH    32

typedef __attribute__((ext_vector_type(8)))  short  bf16x8;
typedef __attribute__((ext_vector_type(8)))  ushort u16x8;
typedef __attribute__((ext_vector_type(4)))  float  f32x4;
typedef __attribute__((ext_vector_type(16))) float  f32x16;

__device__ __forceinline__ float bf2f(ushort u) {
  union { float f; unsigned int i; } x; x.i = ((unsigned int)u) << 16; return x.f;
}
__device__ __forceinline__ ushort f2bf(float f) {
  union { float f; unsigned int i; } x; x.f = f;
  unsigned int r = x.i + 0x7fffu + ((x.i >> 16) & 1u);
  return (ushort)(r >> 16);
}
__device__ __forceinline__ float sigmoidf_(float x) {
  return 1.0f / (1.0f + __expf(-x));
}
__device__ __forceinline__ void load_lds16(const void* g, void* s) {
  __builtin_amdgcn_global_load_lds(
      (const __attribute__((address_space(1))) void*)g,
      (__attribute__((address_space(3))) void*)s, 16, 0, 0);
}

// LDS map (flat, ushort units): A slot s(0..2) half h, B slot s(0..1) half h.
#define AOFF(s,h) ((((s)*2)+(h))*8192)
#define BOFF(s,h) (49152 + (((s)*2)+(h))*8192)

// ------------- weight pre-convert -> bf16, with interleave remap -----------
// dst layout (elems): [0,1M) wr | [1M,2M) wog | [2M,4M) wig_wi interleaved
// (per 128-col group g: rows g*256..+127 = wig, +128..+255 = wi) |
// [4M,5M) wo | [5M,7M) ffn_wg/ffn_wi interleaved.  y==7: ffn_wo -> dst2.
__global__ __launch_bounds__(256)
void cvt_weights(const float* __restrict__ w0, const float* __restrict__ w1,
                 const float* __restrict__ w2, const float* __restrict__ w3,
                 const float* __restrict__ w4, const float* __restrict__ w5,
                 const float* __restrict__ w6, const float* __restrict__ w7,
                 ushort* __restrict__ dst, ushort* __restrict__ dst2)
{
  const float* src; size_t base; int il; ushort* d = dst;
  switch (blockIdx.y) {
    case 0: src = w0; base = 0;       il = 0; break;  // wr
    case 1: src = w1; base = 1048576; il = 0; break;  // wog
    case 2: src = w2; base = 2097152; il = 1; break;  // wig (gate)
    case 3: src = w3; base = 2097152; il = 2; break;  // wi  (value)
    case 4: src = w4; base = 5242880; il = 1; break;  // ffn_wg
    case 5: src = w5; base = 5242880; il = 2; break;  // ffn_wi
    case 6: src = w6; base = 4194304; il = 0; break;  // wo
    default: src = w7; base = 0; il = 0; d = dst2; break; // ffn_wo
  }
  const int i = blockIdx.x * 256 + threadIdx.x;           // [0, 262144)
  const size_t e = (size_t)i * 4;
  size_t off;
  if (il == 0) off = base + e;
  else {
    const int row = (int)(e >> 10), col = (int)(e & 1023);
    const int nr = ((row >> 7) << 8) + (row & 127) + (il == 2 ? 128 : 0);
    off = base + (size_t)nr * 1024 + col;
  }
  const float4 v = *(const float4*)(src + e);
  ushort4 o; o.x = f2bf(v.x); o.y = f2bf(v.y); o.z = f2bf(v.z); o.w = f2bf(v.w);
  *(ushort4*)(d + off) = o;
}

// -------- RMSNorm: 2 rows per block, 8 elems/thread, 16B loads/stores ------
template<bool IN_F32>
__global__ __launch_bounds__(256)
void rmsnorm_k(const void* __restrict__ xin, const float* __restrict__ w,
               ushort* __restrict__ y)
{
  __shared__ float red[4];
  const int tid = threadIdx.x;
  const int rh = tid >> 7;                 // row within block
  const int rr = tid & 127;
  const int row = blockIdx.x * 2 + rh;
  const size_t base = (size_t)row * DIM + rr * 8;
  float v[8];
  if (IN_F32) {
    const float4 a = *(const float4*)((const float*)xin + base);
    const float4 b = *(const float4*)((const float*)xin + base + 4);
    v[0]=a.x; v[1]=a.y; v[2]=a.z; v[3]=a.w;
    v[4]=b.x; v[5]=b.y; v[6]=b.z; v[7]=b.w;
  } else {
    const u16x8 xv = *(const u16x8*)((const ushort*)xin + base);
#pragma unroll
    for (int i = 0; i < 8; ++i) v[i] = bf2f(xv[i]);
  }
  float ss = 0.f;
#pragma unroll
  for (int i = 0; i < 8; ++i) ss += v[i] * v[i];
  for (int o = 32; o > 0; o >>= 1) ss += __shfl_down(ss, o, 64);
  const int wave = tid >> 6;
  if ((tid & 63) == 0) red[wave] = ss;
  __syncthreads();
  const float sum = red[rh * 2] + red[rh * 2 + 1];
  const float scale = rsqrtf(sum * (1.0f / DIM) + 1e-6f);
  const float4 wa = *(const float4*)(w + rr * 8);
  const float4 wb = *(const float4*)(w + rr * 8 + 4);
  u16x8 o;
  o[0] = f2bf(v[0] * scale * wa.x); o[1] = f2bf(v[1] * scale * wa.y);
  o[2] = f2bf(v[2] * scale * wa.z); o[3] = f2bf(v[3] * scale * wa.w);
  o[4] = f2bf(v[4] * scale * wb.x); o[5] = f2bf(v[5] * scale * wb.y);
  o[6] = f2bf(v[6] * scale * wb.z); o[7] = f2bf(v[7] * scale * wb.w);
  *(u16x8*)(y + base) = o;
}

// =================== 256^2 1-barrier/phase 32x32-MFMA GEMM ==================
// C[r,n] = sum_k A[r,k] * W[n,k].  256x256 tile, BK=64, 8 waves (2M x 4N),
// 512 threads.  Per-wave output 128x64 = 4x2 tiles of 32x32.  B fragments
// for the whole K-tile loaded at q0 (bfa[4][2], regs); per-q: 4 A reads.
// Stage schedule & vmcnt identical to the proven round-9 kernel:
//   q0: B1(kt+1), q1: A0(kt+2), q2: A1(kt+2), q3: B0(kt+2) + vmcnt(6)
//   (vmcnt(0) at kt==14).  One barrier per phase; no trailing barrier.
// A triple-buffered, B double-buffered (160 KiB).  T2 XOR-swizzle.
//
// MODE 1: out bf16 = v + auxf[idx]            (fp32 aux)
// MODE 3: out fp32 = v + bf2f(auxb[idx])
// MODE 5: gated interleaved: W panel rows 0-127 gate, 128-255 value;
//         out bf16[cols bn*128..+128) = value * sigmoid(gate + bias)
// MODE 6: bn>>2==0: r=sig(+bias); ==1: og=sig(+bias2)->outb2;
//         bn>=8: gated as MODE5 with bias3 -> outb3, cols (bn-8)*128.
template<int MODE>
__global__ __launch_bounds__(512, 2)
void gemm8(const ushort* __restrict__ A, const ushort* __restrict__ W,
           const float* __restrict__ bias, const float* __restrict__ auxf,
           const ushort* __restrict__ auxb, ushort* __restrict__ outb,
           float* __restrict__ outf,
           const float* __restrict__ bias2, const float* __restrict__ bias3,
           ushort* __restrict__ outb2, ushort* __restrict__ outb3)
{
  __shared__ __align__(16) ushort lds[81920];   // 160 KiB
  const int tid  = threadIdx.x;
  const int bm = blockIdx.x, bn = blockIdx.y;
  const int wave = tid >> 6, lane = tid & 63;
  const int wm = wave >> 2, wn = wave & 3;            // 2M x 4N waves
  const int l31 = lane & 31, lhi = lane >> 5, l7 = lane & 7;

  const ushort* Ab = A + (size_t)bm * (256 * 1024);
  const ushort* Wb = W + (size_t)bn * (256 * 1024);

  f32x16 acc[4][2];
#pragma unroll
  for (int i = 0; i < 4; ++i)
#pragma unroll
    for (int j = 0; j < 2; ++j)
#pragma unroll
      for (int k = 0; k < 16; ++k) acc[i][j][k] = 0.f;

  // hoisted per-thread staging offsets (2 loads per half-tile stage)
  const int ci0 = tid, ci1 = tid + 512;
  const size_t gs0 = (size_t)(ci0 >> 3) * 1024 + (size_t)(((ci0 & 7) ^ ((ci0 >> 3) & 7)) << 3);
  const size_t gs1 = (size_t)(ci1 >> 3) * 1024 + (size_t)(((ci1 & 7) ^ ((ci1 >> 3) & 7)) << 3);
  auto stage = [&](const ushort* __restrict__ src, int loff) {
    load_lds16(src + gs0, &lds[loff + ci0 * 8]);
    load_lds16(src + gs1, &lds[loff + ci1 * 8]);
  };

  // prologue: A(0), B(0), A(1), B0(1); vmcnt(6) -> A(0)+B(0) landed.
  stage(Ab,               AOFF(0,0));
  stage(Ab + 131072,      AOFF(0,1));
  stage(Wb,               BOFF(0,0));
  stage(Wb + 131072,      BOFF(0,1));
  stage(Ab + 64,          AOFF(1,0));
  stage(Ab + 131072 + 64, AOFF(1,1));
  stage(Wb + 64,          BOFF(1,0));
  asm volatile("s_waitcnt vmcnt(6)" ::: "memory");
  __builtin_amdgcn_s_barrier();

  int kt3 = 0;                                        // kt % 3
  for (int kt = 0; kt < 16; ++kt) {
    const ushort* Ah = &lds[AOFF(kt3, wm)];
    const ushort* Bh = &lds[BOFF(kt & 1, wn >> 1)];
    const int kt2s = (kt3 >= 1) ? kt3 - 1 : 2;        // (kt+2) % 3
    const int brow0 = (wn & 1) * 64;
    bf16x8 bfa[4][2];                                 // [k-slice][nt], regs
#pragma unroll
    for (int q = 0; q < 4; ++q) {                     // q = 16-wide k-slice
      if (q == 0) {
#pragma unroll
        for (int qq = 0; qq < 4; ++qq)
#pragma unroll
          for (int nt = 0; nt < 2; ++nt)
            bfa[qq][nt] = *(const bf16x8*)
                &Bh[(brow0 + nt * 32 + l31) * 64 +
                    (((qq * 2 + lhi) ^ l7) << 3)];
      }
      bf16x8 af[4];
#pragma unroll
      for (int mt = 0; mt < 4; ++mt)
        af[mt] = *(const bf16x8*)
            &Ah[(mt * 32 + l31) * 64 + (((q * 2 + lhi) ^ l7) << 3)];
      if (q == 0 && kt + 1 < 16)
        stage(Wb + 131072 + (kt + 1) * 64, BOFF((kt + 1) & 1, 1)); // B1(kt+1)
      if (q == 1 && kt + 2 < 16)
        stage(Ab + (kt + 2) * 64,          AOFF(kt2s, 0));         // A0(kt+2)
      if (q == 2 && kt + 2 < 16)
        stage(Ab + 131072 + (kt + 2) * 64, AOFF(kt2s, 1));         // A1(kt+2)
      if (q == 3) {
        if (kt + 2 < 16)
          stage(Wb + (kt + 2) * 64,        BOFF(kt & 1, 0));       // B0(kt+2)
        if (kt < 14)       asm volatile("s_waitcnt vmcnt(6)" ::: "memory");
        else if (kt == 14) asm volatile("s_waitcnt vmcnt(0)" ::: "memory");
      }
      __builtin_amdgcn_s_barrier();
      asm volatile("s_waitcnt lgkmcnt(0)" ::: "memory");
      __builtin_amdgcn_s_setprio(1);
#pragma unroll
      for (int mt = 0; mt < 4; ++mt)
#pragma unroll
        for (int nt = 0; nt < 2; ++nt)
          acc[mt][nt] = __builtin_amdgcn_mfma_f32_32x32x16_bf16(
              af[mt], bfa[q][nt], acc[mt][nt], 0, 0, 0);
      __builtin_amdgcn_s_setprio(0);
      // no trailing barrier: waves may skew into the next phase's reads.
    }
    kt3 = (kt3 == 2) ? 0 : kt3 + 1;
  }

  // ---------------- coalesced LDS-transposed epilogue ----------------
  __builtin_amdgcn_s_barrier();
  float* C = (float*)lds;                             // [128][256] fp32
  const bool gated = (MODE == 5) || (MODE == 6 && bn >= 8);
#pragma unroll 1
  for (int h = 0; h < 2; ++h) {
    if (wm == h) {
      const int cb = wn * 64;
      // 32x32 C/D layout: col = l31, row = (reg&3) + 8*(reg>>2) + 4*lhi
#pragma unroll
      for (int mt = 0; mt < 4; ++mt)
#pragma unroll
        for (int nt = 0; nt < 2; ++nt)
#pragma unroll
          for (int rq = 0; rq < 4; ++rq)
#pragma unroll
            for (int rr = 0; rr < 4; ++rr) {
              const int rw = mt * 32 + rr + 8 * rq + 4 * lhi;
              const int cw = cb + nt * 32 + l31;
              C[rw * 256 + cw] = acc[mt][nt][rq * 4 + rr];
            }
    }
    __syncthreads();
    if (gated) {
      const int outcol = (MODE == 6) ? (bn - 8) * 128 : bn * 128;
      const float* bp = (MODE == 6) ? bias3 : bias;
      ushort* ob = (MODE == 6) ? outb3 : outb;
#pragma unroll 1
      for (int sp = 0; sp < 4; ++sp) {
        const int lin = sp * 4096 + tid * 8;          // [0, 16384)
        const int row = lin >> 7, c8 = lin & 127;
        const float4 gA = *(const float4*)&C[row * 256 + c8];
        const float4 gB = *(const float4*)&C[row * 256 + c8 + 4];
        const float4 vA = *(const float4*)&C[row * 256 + c8 + 128];
        const float4 vB = *(const float4*)&C[row * 256 + c8 + 132];
        const float4 b0 = *(const float4*)(bp + outcol + c8);
        const float4 b1 = *(const float4*)(bp + outcol + c8 + 4);
        const int rg = bm * 256 + h * 128 + row;
        const size_t gidx = (size_t)rg * 1024 + outcol + c8;
        u16x8 o;
        o[0] = f2bf(vA.x * sigmoidf_(gA.x + b0.x));
        o[1] = f2bf(vA.y * sigmoidf_(gA.y + b0.y));
        o[2] = f2bf(vA.z * sigmoidf_(gA.z + b0.z));
        o[3] = f2bf(vA.w * sigmoidf_(gA.w + b0.w));
        o[4] = f2bf(vB.x * sigmoidf_(gB.x + b1.x));
        o[5] = f2bf(vB.y * sigmoidf_(gB.y + b1.y));
        o[6] = f2bf(vB.z * sigmoidf_(gB.z + b1.z));
        o[7] = f2bf(vB.w * sigmoidf_(gB.w + b1.w));
        *(u16x8*)(ob + gidx) = o;
      }
    } else {
#pragma unroll 1
      for (int sp = 0; sp < 8; ++sp) {
        const int lin = sp * 4096 + tid * 8;
        const int row = lin >> 8, c8 = lin & 255;
        const float4 vA = *(const float4*)&C[row * 256 + c8];
        const float4 vB = *(const float4*)&C[row * 256 + c8 + 4];
        const int rg = bm * 256 + h * 128 + row;
        if (MODE == 6) {
          const int grp = bn >> 2;                    // 0 -> r, 1 -> og
          ushort* ob = grp ? outb2 : outb;
          const float* bp = grp ? bias2 : bias;
          const int colbase = (bn & 3) * 256;
          const size_t gidx = (size_t)rg * 1024 + colbase + c8;
          const float4 b0 = *(const float4*)(bp + colbase + c8);
          const float4 b1 = *(const float4*)(bp + colbase + c8 + 4);
          u16x8 o;
          o[0] = f2bf(sigmoidf_(vA.x + b0.x)); o[1] = f2bf(sigmoidf_(vA.y + b0.y));
          o[2] = f2bf(sigmoidf_(vA.z + b0.z)); o[3] = f2bf(sigmoidf_(vA.w + b0.w));
          o[4] = f2bf(sigmoidf_(vB.x + b1.x)); o[5] = f2bf(sigmoidf_(vB.y + b1.y));
          o[6] = f2bf(sigmoidf_(vB.z + b1.z)); o[7] = f2bf(sigmoidf_(vB.w + b1.w));
          *(u16x8*)(ob + gidx) = o;
        } else if (MODE == 1) {
          const size_t gidx = (size_t)rg * 1024 + bn * 256 + c8;
          const float4 a0 = *(const float4*)(auxf + gidx);
          const float4 a1 = *(const float4*)(auxf + gidx + 4);
          u16x8 o;
          o[0] = f2bf(vA.x + a0.x); o[1] = f2bf(vA.y + a0.y);
          o[2] = f2bf(vA.z + a0.z); o[3] = f2bf(vA.w + a0.w);
          o[4] = f2bf(vB.x + a1.x); o[5] = f2bf(vB.y + a1.y);
          o[6] = f2bf(vB.z + a1.z); o[7] = f2bf(vB.w + a1.w);
          *(u16x8*)(outb + gidx) = o;
        } else {                                      // MODE 3
          const size_t gidx = (size_t)rg * 1024 + bn * 256 + c8;
          const u16x8 a8 = *(const u16x8*)(auxb + gidx);
          float4 o0, o1;
          o0.x = vA.x + bf2f(a8[0]); o0.y = vA.y + bf2f(a8[1]);
          o0.z = vA.z + bf2f(a8[2]); o0.w = vA.w + bf2f(a8[3]);
          o1.x = vB.x + bf2f(a8[4]); o1.y = vB.y + bf2f(a8[5]);
          o1.z = vB.z + bf2f(a8[6]); o1.w = vB.w + bf2f(a8[7]);
          *(float4*)(outf + gidx) = o0;
          *(float4*)(outf + gidx + 4) = o1;
        }
      }
    }
    if (h == 0) __syncthreads();
  }
}

// ------------- linear recurrence h_t = xg_t + r_t*h_{t-1}, chunked ----------
__global__ __launch_bounds__(256)
void linrec_passA(ushort* __restrict__ xg, const ushort* __restrict__ r,
                  float* __restrict__ cL, float* __restrict__ cP)
{
  const int g = blockIdx.x * 256 + threadIdx.x;   // [0, 131072)
  const int m4 = (g & 255) << 2;
  const int bc = g >> 8;                          // [0, 512)
  const int b = bc >> 7, c = bc & 127;
  const size_t base = ((size_t)(b * TSEQ + c * TCH)) * MDIM + m4;
  float h0 = 0.f, h1 = 0.f, h2 = 0.f, h3 = 0.f;
  float p0 = 1.f, p1 = 1.f, p2 = 1.f, p3 = 1.f;
  for (int t = 0; t < TCH; ++t) {
    const size_t idx = base + (size_t)t * MDIM;
    const ushort4 xv = *(const ushort4*)&xg[idx];
    const ushort4 rv = *(const ushort4*)&r[idx];
    const float r0 = bf2f(rv.x), r1 = bf2f(rv.y), r2 = bf2f(rv.z), r3 = bf2f(rv.w);
    h0 = fmaf(r0, h0, bf2f(xv.x)); p0 *= r0;
    h1 = fmaf(r1, h1, bf2f(xv.y)); p1 *= r1;
    h2 = fmaf(r2, h2, bf2f(xv.z)); p2 *= r2;
    h3 = fmaf(r3, h3, bf2f(xv.w)); p3 *= r3;
    ushort4 o; o.x = f2bf(h0); o.y = f2bf(h1); o.z = f2bf(h2); o.w = f2bf(h3);
    *(ushort4*)&xg[idx] = o;
  }
  const size_t cb = (size_t)c * 4096 + b * MDIM + m4;
  float4 L4; L4.x = h0; L4.y = h1; L4.z = h2; L4.w = h3;
  float4 P4; P4.x = p0; P4.y = p1; P4.z = p2; P4.w = p3;
  *(float4*)&cL[cb] = L4;
  *(float4*)&cP[cb] = P4;
}

__global__ __launch_bounds__(64)
void linrec_passB(const float* __restrict__ cL, const float* __restrict__ cP,
                  const float* __restrict__ mem, float* __restrict__ cIn,
                  float* __restrict__ memout)
{
  const int g = blockIdx.x * 64 + threadIdx.x;    // [0,4096)
  float carry = mem[g];
#pragma unroll 4
  for (int c = 0; c < NCHUNK; ++c) {
    cIn[c * 4096 + g] = carry;
    carry = fmaf(cP[c * 4096 + g], carry, cL[c * 4096 + g]);
  }
  memout[g] = carry;
}

__global__ __launch_bounds__(256)
void linrec_passC(const ushort* __restrict__ L, const ushort* __restrict__ r,
                  const ushort* __restrict__ og, const float* __restrict__ cIn,
                  ushort* __restrict__ s)
{
  const int g = blockIdx.x * 256 + threadIdx.x;   // [0, 131072)
  const int m4 = (g & 255) << 2;
  const int bc = g >> 8;
  const int b = bc >> 7, c = bc & 127;
  const size_t base = ((size_t)(b * TSEQ + c * TCH)) * MDIM + m4;
  const size_t cb = (size_t)c * 4096 + b * MDIM + m4;
  const float4 ci = *(const float4*)&cIn[cb];
  float p0 = 1.f, p1 = 1.f, p2 = 1.f, p3 = 1.f;
  for (int t = 0; t < TCH; ++t) {
    const size_t idx = base + (size_t)t * MDIM;
    const ushort4 rv = *(const ushort4*)&r[idx];
    const ushort4 lv = *(const ushort4*)&L[idx];
    const ushort4 ov = *(const ushort4*)&og[idx];
    p0 *= bf2f(rv.x); p1 *= bf2f(rv.y); p2 *= bf2f(rv.z); p3 *= bf2f(rv.w);
    const float a0 = fmaf(p0, ci.x, bf2f(lv.x));
    const float a1 = fmaf(p1, ci.y, bf2f(lv.y));
    const float a2 = fmaf(p2, ci.z, bf2f(lv.z));
    const float a3 = fmaf(p3, ci.w, bf2f(lv.w));
    ushort4 o;
    o.x = f2bf(a0 / (1.0f + fabsf(a0)) * bf2f(ov.x));
    o.y = f2bf(a1 / (1.0f + fabsf(a1)) * bf2f(ov.y));
    o.z = f2bf(a2 / (1.0f + fabsf(a2)) * bf2f(ov.z));
    o.w = f2bf(a3 / (1.0f + fabsf(a3)) * bf2f(ov.w));
    *(ushort4*)&s[idx] = o;
  }
}

// ---------------- launch ----------------
extern "C" void kernel_launch(void* const* d_in, const int* in_sizes, int n_in,
                              void* d_out, int out_size, void* d_ws, size_t ws_size,
                              hipStream_t stream)
{
  const float* x        = (const float*)d_in[0];
  const float* mem      = (const float*)d_in[1];
  const float* norm_w   = (const float*)d_in[2];
  const float* wr_w     = (const float*)d_in[3];
  const float* wr_b     = (const float*)d_in[4];
  const float* wi_w     = (const float*)d_in[5];
  const float* wig_w    = (const float*)d_in[6];
  const float* wig_b    = (const float*)d_in[7];
  const float* wog_w    = (const float*)d_in[8];
  const float* wog_b    = (const float*)d_in[9];
  const float* wo_w     = (const float*)d_in[10];
  const float* ffnorm_w = (const float*)d_in[11];
  const float* ffn_wi_w = (const float*)d_in[12];
  const float* ffn_wg_w = (const float*)d_in[13];
  const float* ffn_wg_b = (const float*)d_in[14];
  const float* ffn_wo_w = (const float*)d_in[15];
  float* outF = (float*)d_out;

  // d_out scratch (dead until final GEMM / passB):
  ushort* xgL  = (ushort*)d_out;                        // [0,32MB): xg -> L
  ushort* wbf  = (ushort*)((char*)d_out + 33554432ULL); // [32,46MB): 7M bf16 W
  float*  cL   = (float*)((char*)d_out + 48234496ULL);  // [46,48MB)
  float*  cP   = (float*)((char*)d_out + 50331648ULL);  // [48,50MB)
  float*  cIn  = (float*)((char*)d_out + 52428800ULL);  // [50,52MB)
  float*  memoutF = outF + 16777216;                    // mem_out fp32

  // ws (~97MB):
  char* ws = (char*)d_ws;
  ushort* y   = (ushort*)(ws);                 // 32MB bf16: y -> s -> gf/ff
  ushort* r   = (ushort*)(ws + 33554432ULL);   // 32MB bf16: r -> z
  ushort* og  = (ushort*)(ws + 67108864ULL);   // 32MB bf16: og -> x1
  ushort* fwo_bf = (ushort*)(ws + 100663296ULL); // 2MB bf16 ffn_wo
  ushort* s   = y;
  ushort* x1  = og;
  ushort* z   = r;
  ushort* gf  = y;                             // ffn ff

  cvt_weights<<<dim3(1024, 8), 256, 0, stream>>>(
      wr_w, wog_w, wig_w, wi_w, ffn_wg_w, ffn_wi_w, wo_w, ffn_wo_w,
      wbf, fwo_bf);

  // sqrll branch: one dispatch -> r, og, xg
  rmsnorm_k<true><<<R_ROWS / 2, 256, 0, stream>>>(x, norm_w, y);
  gemm8<6><<<dim3(64, 16), 512, 0, stream>>>(
      y, wbf, wr_b, nullptr, nullptr, r, nullptr, wog_b, wig_b, og, xgL);
  linrec_passA<<<512, 256, 0, stream>>>(xgL, r, cL, cP);
  linrec_passB<<<64, 64, 0, stream>>>(cL, cP, mem, cIn, memoutF);
  linrec_passC<<<512, 256, 0, stream>>>(xgL, r, og, cIn, s);
  gemm8<1><<<dim3(64, 4), 512, 0, stream>>>(
      s, wbf + 4194304, nullptr, x, nullptr, x1, nullptr,
      nullptr, nullptr, nullptr, nullptr);
  // ffn branch: gated in one dispatch -> ff
  rmsnorm_k<false><<<R_ROWS / 2, 256, 0, stream>>>(x1, ffnorm_w, z);
  gemm8<5><<<dim3(64, 8), 512, 0, stream>>>(
      z, wbf + 5242880, ffn_wg_b, nullptr, nullptr, gf, nullptr,
      nullptr, nullptr, nullptr, nullptr);
  gemm8<3><<<dim3(64, 4), 512, 0, stream>>>(
      gf, fwo_bf, nullptr, nullptr, x1, nullptr, outF,
      nullptr, nullptr, nullptr, nullptr);
}

// Round 8
// 535.878 us; speedup vs baseline: 1.0238x; 1.0238x over previous
//
#include <hip/hip_runtime.h>
#include <stdint.h>

// B=4, T=4096, D=1024, M=1024.  I/O fp32.  Round 13:
// (1) gemm8 REVERTED verbatim to the round-9/round-4 proven 16x16x32 kernel
//     (152.9 us MODE6, 1.05e6 conflicts).  Round-10/11's 32x32 experiment is
//     closed: MFMA-busy time identical (60.7 vs 60.4 us) but +13x LDS bank
//     conflicts (+22 us/dispatch) -> MFMA shape is not the binding resource.
// (2) Round-7 peripherals kept: merged cvt (8 slices), 2-row rmsnorm,
//     64-wide passB.
// (3) Linrec reshaped TCH=16 / NCHUNK=256 (1024 blocks, 4/CU): half the
//     serial chain, 2x TLP; cL/cP/cIn now 4 MB each at [46,58) MB of d_out.

#define R_ROWS 16384
#define DIM    1024
#define MDIM   1024
#define TSEQ   4096
#define NCHUNK 256
#define TCH    16

typedef __attribute__((ext_vector_type(8)))  short  bf16x8;
typedef __attribute__((ext_vector_type(8)))  ushort u16x8;
typedef __attribute__((ext_vector_type(4)))  float  f32x4;

__device__ __forceinline__ float bf2f(ushort u) {
  union { float f; unsigned int i; } x; x.i = ((unsigned int)u) << 16; return x.f;
}
__device__ __forceinline__ ushort f2bf(float f) {
  union { float f; unsigned int i; } x; x.f = f;
  unsigned int r = x.i + 0x7fffu + ((x.i >> 16) & 1u);
  return (ushort)(r >> 16);
}
__device__ __forceinline__ float sigmoidf_(float x) {
  return 1.0f / (1.0f + __expf(-x));
}
__device__ __forceinline__ void load_lds16(const void* g, void* s) {
  __builtin_amdgcn_global_load_lds(
      (const __attribute__((address_space(1))) void*)g,
      (__attribute__((address_space(3))) void*)s, 16, 0, 0);
}

// LDS map (flat, ushort units): A slot s(0..2) half h, B slot s(0..1) half h.
#define AOFF(s,h) ((((s)*2)+(h))*8192)
#define BOFF(s,h) (49152 + (((s)*2)+(h))*8192)

// ------------- weight pre-convert -> bf16, with interleave remap -----------
// dst layout (elems): [0,1M) wr | [1M,2M) wog | [2M,4M) wig_wi interleaved
// (per 128-col group g: rows g*256..+127 = wig, +128..+255 = wi) |
// [4M,5M) wo | [5M,7M) ffn_wg/ffn_wi interleaved.  y==7: ffn_wo -> dst2.
__global__ __launch_bounds__(256)
void cvt_weights(const float* __restrict__ w0, const float* __restrict__ w1,
                 const float* __restrict__ w2, const float* __restrict__ w3,
                 const float* __restrict__ w4, const float* __restrict__ w5,
                 const float* __restrict__ w6, const float* __restrict__ w7,
                 ushort* __restrict__ dst, ushort* __restrict__ dst2)
{
  const float* src; size_t base; int il; ushort* d = dst;
  switch (blockIdx.y) {
    case 0: src = w0; base = 0;       il = 0; break;  // wr
    case 1: src = w1; base = 1048576; il = 0; break;  // wog
    case 2: src = w2; base = 2097152; il = 1; break;  // wig (gate)
    case 3: src = w3; base = 2097152; il = 2; break;  // wi  (value)
    case 4: src = w4; base = 5242880; il = 1; break;  // ffn_wg
    case 5: src = w5; base = 5242880; il = 2; break;  // ffn_wi
    case 6: src = w6; base = 4194304; il = 0; break;  // wo
    default: src = w7; base = 0; il = 0; d = dst2; break; // ffn_wo
  }
  const int i = blockIdx.x * 256 + threadIdx.x;           // [0, 262144)
  const size_t e = (size_t)i * 4;
  size_t off;
  if (il == 0) off = base + e;
  else {
    const int row = (int)(e >> 10), col = (int)(e & 1023);
    const int nr = ((row >> 7) << 8) + (row & 127) + (il == 2 ? 128 : 0);
    off = base + (size_t)nr * 1024 + col;
  }
  const float4 v = *(const float4*)(src + e);
  ushort4 o; o.x = f2bf(v.x); o.y = f2bf(v.y); o.z = f2bf(v.z); o.w = f2bf(v.w);
  *(ushort4*)(d + off) = o;
}

// -------- RMSNorm: 2 rows per block, 8 elems/thread, 16B loads/stores ------
template<bool IN_F32>
__global__ __launch_bounds__(256)
void rmsnorm_k(const void* __restrict__ xin, const float* __restrict__ w,
               ushort* __restrict__ y)
{
  __shared__ float red[4];
  const int tid = threadIdx.x;
  const int rh = tid >> 7;                 // row within block
  const int rr = tid & 127;
  const int row = blockIdx.x * 2 + rh;
  const size_t base = (size_t)row * DIM + rr * 8;
  float v[8];
  if (IN_F32) {
    const float4 a = *(const float4*)((const float*)xin + base);
    const float4 b = *(const float4*)((const float*)xin + base + 4);
    v[0]=a.x; v[1]=a.y; v[2]=a.z; v[3]=a.w;
    v[4]=b.x; v[5]=b.y; v[6]=b.z; v[7]=b.w;
  } else {
    const u16x8 xv = *(const u16x8*)((const ushort*)xin + base);
#pragma unroll
    for (int i = 0; i < 8; ++i) v[i] = bf2f(xv[i]);
  }
  float ss = 0.f;
#pragma unroll
  for (int i = 0; i < 8; ++i) ss += v[i] * v[i];
  for (int o = 32; o > 0; o >>= 1) ss += __shfl_down(ss, o, 64);
  const int wave = tid >> 6;
  if ((tid & 63) == 0) red[wave] = ss;
  __syncthreads();
  const float sum = red[rh * 2] + red[rh * 2 + 1];
  const float scale = rsqrtf(sum * (1.0f / DIM) + 1e-6f);
  const float4 wa = *(const float4*)(w + rr * 8);
  const float4 wb = *(const float4*)(w + rr * 8 + 4);
  u16x8 o;
  o[0] = f2bf(v[0] * scale * wa.x); o[1] = f2bf(v[1] * scale * wa.y);
  o[2] = f2bf(v[2] * scale * wa.z); o[3] = f2bf(v[3] * scale * wa.w);
  o[4] = f2bf(v[4] * scale * wb.x); o[5] = f2bf(v[5] * scale * wb.y);
  o[6] = f2bf(v[6] * scale * wb.z); o[7] = f2bf(v[7] * scale * wb.w);
  *(u16x8*)(y + base) = o;
}

// ======================= 256^2 1-barrier/phase bf16 GEMM ====================
// (round-9 proven kernel, verbatim)  C[r,n] = sum_k A[r,k] * W[n,k].
// 256x256 tile, BK=64, 8 waves (2M x 4N), 512 threads.  16x16x32 MFMA.
// A triple-buffered, B double-buffered (160 KiB LDS).  Per phase: {reads;
// stage; [vmcnt@q3]; BAR; lgkm(0); setprio(1); 16 MFMA; setprio(0)} — no
// trailing barrier.  Stages: q0:B1(kt+1) q1:A0(kt+2) q2:A1(kt+2) q3:B0(kt+2),
// vmcnt(6) steady / vmcnt(0)@kt==14.  T2 XOR-swizzle on staging+reads.
//
// MODE 1: out bf16 = v + auxf[idx]            (fp32 aux)
// MODE 3: out fp32 = v + bf2f(auxb[idx])
// MODE 5: gated interleaved: W panel rows 0-127 gate, 128-255 value;
//         out bf16[cols bn*128..+128) = value * sigmoid(gate + bias)
// MODE 6: bn>>2==0: r=sig(+bias); ==1: og=sig(+bias2)->outb2;
//         bn>=8: gated as MODE5 with bias3 -> outb3, cols (bn-8)*128.
template<int MODE>
__global__ __launch_bounds__(512, 2)
void gemm8(const ushort* __restrict__ A, const ushort* __restrict__ W,
           const float* __restrict__ bias, const float* __restrict__ auxf,
           const ushort* __restrict__ auxb, ushort* __restrict__ outb,
           float* __restrict__ outf,
           const float* __restrict__ bias2, const float* __restrict__ bias3,
           ushort* __restrict__ outb2, ushort* __restrict__ outb3)
{
  __shared__ __align__(16) ushort lds[81920];   // 160 KiB
  const int tid  = threadIdx.x;
  const int bm = blockIdx.x, bn = blockIdx.y;
  const int wave = tid >> 6, lane = tid & 63;
  const int wm = wave >> 2, wn = wave & 3;            // 2M x 4N waves
  const int quad = lane >> 4, l16 = lane & 15;
  const int axor = l16 & 7;

  const ushort* Ab = A + (size_t)bm * (256 * 1024);
  const ushort* Wb = W + (size_t)bn * (256 * 1024);

  f32x4 acc[8][4];
#pragma unroll
  for (int i = 0; i < 8; ++i)
#pragma unroll
    for (int j = 0; j < 4; ++j) acc[i][j] = (f32x4){0.f, 0.f, 0.f, 0.f};

  // hoisted per-thread staging offsets (2 loads per half-tile stage)
  const int ci0 = tid, ci1 = tid + 512;
  const size_t gs0 = (size_t)(ci0 >> 3) * 1024 + (size_t)(((ci0 & 7) ^ ((ci0 >> 3) & 7)) << 3);
  const size_t gs1 = (size_t)(ci1 >> 3) * 1024 + (size_t)(((ci1 & 7) ^ ((ci1 >> 3) & 7)) << 3);
  auto stage = [&](const ushort* __restrict__ src, int loff) {
    load_lds16(src + gs0, &lds[loff + ci0 * 8]);
    load_lds16(src + gs1, &lds[loff + ci1 * 8]);
  };

  // prologue: A(0), B(0), A(1), B0(1); vmcnt(6) -> A(0)+B(0) landed.
  stage(Ab,               AOFF(0,0));
  stage(Ab + 131072,      AOFF(0,1));
  stage(Wb,               BOFF(0,0));
  stage(Wb + 131072,      BOFF(0,1));
  stage(Ab + 64,          AOFF(1,0));
  stage(Ab + 131072 + 64, AOFF(1,1));
  stage(Wb + 64,          BOFF(1,0));
  asm volatile("s_waitcnt vmcnt(6)" ::: "memory");
  __builtin_amdgcn_s_barrier();

  int kt3 = 0;                                        // kt % 3
  for (int kt = 0; kt < 16; ++kt) {
    const ushort* Ah = &lds[AOFF(kt3, wm)];
    const ushort* Bh = &lds[BOFF(kt & 1, wn >> 1)];
    const int kt2s = (kt3 >= 1) ? kt3 - 1 : 2;        // (kt+2) % 3
    const int brow0 = (wn & 1) * 64;
    bf16x8 bfr[4][2];
#pragma unroll
    for (int q = 0; q < 4; ++q) {
      if (q == 0) {
#pragma unroll
        for (int j = 0; j < 4; ++j)
#pragma unroll
          for (int ks = 0; ks < 2; ++ks)
            bfr[j][ks] = *(const bf16x8*)
                &Bh[(brow0 + j * 16 + l16) * 64 +
                    (((ks * 4 + quad) ^ axor) << 3)];
      }
      bf16x8 af[2][2];
#pragma unroll
      for (int p = 0; p < 2; ++p)
#pragma unroll
        for (int ks = 0; ks < 2; ++ks)
          af[p][ks] = *(const bf16x8*)
              &Ah[((2 * q + p) * 16 + l16) * 64 +
                  (((ks * 4 + quad) ^ axor) << 3)];
      if (q == 0 && kt + 1 < 16)
        stage(Wb + 131072 + (kt + 1) * 64, BOFF((kt + 1) & 1, 1)); // B1(kt+1)
      if (q == 1 && kt + 2 < 16)
        stage(Ab + (kt + 2) * 64,          AOFF(kt2s, 0));         // A0(kt+2)
      if (q == 2 && kt + 2 < 16)
        stage(Ab + 131072 + (kt + 2) * 64, AOFF(kt2s, 1));         // A1(kt+2)
      if (q == 3) {
        if (kt + 2 < 16)
          stage(Wb + (kt + 2) * 64,        BOFF(kt & 1, 0));       // B0(kt+2)
        if (kt < 14)       asm volatile("s_waitcnt vmcnt(6)" ::: "memory");
        else if (kt == 14) asm volatile("s_waitcnt vmcnt(0)" ::: "memory");
      }
      __builtin_amdgcn_s_barrier();
      asm volatile("s_waitcnt lgkmcnt(0)" ::: "memory");
      __builtin_amdgcn_s_setprio(1);
#pragma unroll
      for (int p = 0; p < 2; ++p)
#pragma unroll
        for (int j = 0; j < 4; ++j)
#pragma unroll
          for (int ks = 0; ks < 2; ++ks)
            acc[2 * q + p][j] = __builtin_amdgcn_mfma_f32_16x16x32_bf16(
                af[p][ks], bfr[j][ks], acc[2 * q + p][j], 0, 0, 0);
      __builtin_amdgcn_s_setprio(0);
      // no trailing barrier: waves may skew into the next phase's reads.
    }
    kt3 = (kt3 == 2) ? 0 : kt3 + 1;
  }

  // ---------------- coalesced LDS-transposed epilogue ----------------
  __builtin_amdgcn_s_barrier();
  float* C = (float*)lds;                             // [128][256] fp32
  const bool gated = (MODE == 5) || (MODE == 6 && bn >= 8);
#pragma unroll 1
  for (int h = 0; h < 2; ++h) {
    if (wm == h) {
      const int cb = wn * 64;
#pragma unroll
      for (int i = 0; i < 8; ++i)
#pragma unroll
        for (int j = 0; j < 4; ++j)
#pragma unroll
          for (int g = 0; g < 4; ++g) {
            const int rw = i * 16 + quad * 4 + g;
            const int cw = cb + j * 16 + l16;
            C[rw * 256 + (cw ^ (((rw >> 2) & 1) << 4))] = acc[i][j][g];
          }
    }
    __syncthreads();
    if (gated) {
      const int outcol = (MODE == 6) ? (bn - 8) * 128 : bn * 128;
      const float* bp = (MODE == 6) ? bias3 : bias;
      ushort* ob = (MODE == 6) ? outb3 : outb;
#pragma unroll 1
      for (int sp = 0; sp < 4; ++sp) {
        const int lin = sp * 4096 + tid * 8;          // [0, 16384)
        const int row = lin >> 7, c8 = lin & 127;
        const int xr = ((row >> 2) & 1) << 4;
        const int cg = c8 ^ xr;                       // gate cols (0..127)
        const int cv = (c8 + 128) ^ xr;               // value cols (128..255)
        const float4 gA = *(const float4*)&C[row * 256 + cg];
        const float4 gB = *(const float4*)&C[row * 256 + cg + 4];
        const float4 vA = *(const float4*)&C[row * 256 + cv];
        const float4 vB = *(const float4*)&C[row * 256 + cv + 4];
        const float4 b0 = *(const float4*)(bp + outcol + c8);
        const float4 b1 = *(const float4*)(bp + outcol + c8 + 4);
        const int rg = bm * 256 + h * 128 + row;
        const size_t gidx = (size_t)rg * 1024 + outcol + c8;
        u16x8 o;
        o[0] = f2bf(vA.x * sigmoidf_(gA.x + b0.x));
        o[1] = f2bf(vA.y * sigmoidf_(gA.y + b0.y));
        o[2] = f2bf(vA.z * sigmoidf_(gA.z + b0.z));
        o[3] = f2bf(vA.w * sigmoidf_(gA.w + b0.w));
        o[4] = f2bf(vB.x * sigmoidf_(gB.x + b1.x));
        o[5] = f2bf(vB.y * sigmoidf_(gB.y + b1.y));
        o[6] = f2bf(vB.z * sigmoidf_(gB.z + b1.z));
        o[7] = f2bf(vB.w * sigmoidf_(gB.w + b1.w));
        *(u16x8*)(ob + gidx) = o;
      }
    } else {
#pragma unroll 1
      for (int sp = 0; sp < 8; ++sp) {
        const int lin = sp * 4096 + tid * 8;
        const int row = lin >> 8, c8 = lin & 255;
        const int xr = ((row >> 2) & 1) << 4;
        const int cx = c8 ^ xr;
        const float4 vA = *(const float4*)&C[row * 256 + cx];
        const float4 vB = *(const float4*)&C[row * 256 + cx + 4];
        const int rg = bm * 256 + h * 128 + row;
        if (MODE == 6) {
          const int grp = bn >> 2;                    // 0 -> r, 1 -> og
          ushort* ob = grp ? outb2 : outb;
          const float* bp = grp ? bias2 : bias;
          const int colbase = (bn & 3) * 256;
          const size_t gidx = (size_t)rg * 1024 + colbase + c8;
          const float4 b0 = *(const float4*)(bp + colbase + c8);
          const float4 b1 = *(const float4*)(bp + colbase + c8 + 4);
          u16x8 o;
          o[0] = f2bf(sigmoidf_(vA.x + b0.x)); o[1] = f2bf(sigmoidf_(vA.y + b0.y));
          o[2] = f2bf(sigmoidf_(vA.z + b0.z)); o[3] = f2bf(sigmoidf_(vA.w + b0.w));
          o[4] = f2bf(sigmoidf_(vB.x + b1.x)); o[5] = f2bf(sigmoidf_(vB.y + b1.y));
          o[6] = f2bf(sigmoidf_(vB.z + b1.z)); o[7] = f2bf(sigmoidf_(vB.w + b1.w));
          *(u16x8*)(ob + gidx) = o;
        } else if (MODE == 1) {
          const size_t gidx = (size_t)rg * 1024 + bn * 256 + c8;
          const float4 a0 = *(const float4*)(auxf + gidx);
          const float4 a1 = *(const float4*)(auxf + gidx + 4);
          u16x8 o;
          o[0] = f2bf(vA.x + a0.x); o[1] = f2bf(vA.y + a0.y);
          o[2] = f2bf(vA.z + a0.z); o[3] = f2bf(vA.w + a0.w);
          o[4] = f2bf(vB.x + a1.x); o[5] = f2bf(vB.y + a1.y);
          o[6] = f2bf(vB.z + a1.z); o[7] = f2bf(vB.w + a1.w);
          *(u16x8*)(outb + gidx) = o;
        } else {                                      // MODE 3
          const size_t gidx = (size_t)rg * 1024 + bn * 256 + c8;
          const u16x8 a8 = *(const u16x8*)(auxb + gidx);
          float4 o0, o1;
          o0.x = vA.x + bf2f(a8[0]); o0.y = vA.y + bf2f(a8[1]);
          o0.z = vA.z + bf2f(a8[2]); o0.w = vA.w + bf2f(a8[3]);
          o1.x = vB.x + bf2f(a8[4]); o1.y = vB.y + bf2f(a8[5]);
          o1.z = vB.z + bf2f(a8[6]); o1.w = vB.w + bf2f(a8[7]);
          *(float4*)(outf + gidx) = o0;
          *(float4*)(outf + gidx + 4) = o1;
        }
      }
    }
    if (h == 0) __syncthreads();
  }
}

// ------------- linear recurrence h_t = xg_t + r_t*h_{t-1}, chunked ----------
// TCH=16, NCHUNK=256: 262144 threads -> 1024 blocks (4/CU).  4 m per thread.
__global__ __launch_bounds__(256)
void linrec_passA(ushort* __restrict__ xg, const ushort* __restrict__ r,
                  float* __restrict__ cL, float* __restrict__ cP)
{
  const int g = blockIdx.x * 256 + threadIdx.x;   // [0, 262144)
  const int m4 = (g & 255) << 2;
  const int bc = g >> 8;                          // [0, 1024)
  const int b = bc >> 8, c = bc & 255;
  const size_t base = ((size_t)(b * TSEQ + c * TCH)) * MDIM + m4;
  float h0 = 0.f, h1 = 0.f, h2 = 0.f, h3 = 0.f;
  float p0 = 1.f, p1 = 1.f, p2 = 1.f, p3 = 1.f;
  for (int t = 0; t < TCH; ++t) {
    const size_t idx = base + (size_t)t * MDIM;
    const ushort4 xv = *(const ushort4*)&xg[idx];
    const ushort4 rv = *(const ushort4*)&r[idx];
    const float r0 = bf2f(rv.x), r1 = bf2f(rv.y), r2 = bf2f(rv.z), r3 = bf2f(rv.w);
    h0 = fmaf(r0, h0, bf2f(xv.x)); p0 *= r0;
    h1 = fmaf(r1, h1, bf2f(xv.y)); p1 *= r1;
    h2 = fmaf(r2, h2, bf2f(xv.z)); p2 *= r2;
    h3 = fmaf(r3, h3, bf2f(xv.w)); p3 *= r3;
    ushort4 o; o.x = f2bf(h0); o.y = f2bf(h1); o.z = f2bf(h2); o.w = f2bf(h3);
    *(ushort4*)&xg[idx] = o;
  }
  const size_t cb = (size_t)c * 4096 + b * MDIM + m4;
  float4 L4; L4.x = h0; L4.y = h1; L4.z = h2; L4.w = h3;
  float4 P4; P4.x = p0; P4.y = p1; P4.z = p2; P4.w = p3;
  *(float4*)&cL[cb] = L4;
  *(float4*)&cP[cb] = P4;
}

__global__ __launch_bounds__(64)
void linrec_passB(const float* __restrict__ cL, const float* __restrict__ cP,
                  const float* __restrict__ mem, float* __restrict__ cIn,
                  float* __restrict__ memout)
{
  const int g = blockIdx.x * 64 + threadIdx.x;    // [0,4096)
  float carry = mem[g];
#pragma unroll 4
  for (int c = 0; c < NCHUNK; ++c) {
    cIn[c * 4096 + g] = carry;
    carry = fmaf(cP[c * 4096 + g], carry, cL[c * 4096 + g]);
  }
  memout[g] = carry;
}

__global__ __launch_bounds__(256)
void linrec_passC(const ushort* __restrict__ L, const ushort* __restrict__ r,
                  const ushort* __restrict__ og, const float* __restrict__ cIn,
                  ushort* __restrict__ s)
{
  const int g = blockIdx.x * 256 + threadIdx.x;   // [0, 262144)
  const int m4 = (g & 255) << 2;
  const int bc = g >> 8;
  const int b = bc >> 8, c = bc & 255;
  const size_t base = ((size_t)(b * TSEQ + c * TCH)) * MDIM + m4;
  const size_t cb = (size_t)c * 4096 + b * MDIM + m4;
  const float4 ci = *(const float4*)&cIn[cb];
  float p0 = 1.f, p1 = 1.f, p2 = 1.f, p3 = 1.f;
  for (int t = 0; t < TCH; ++t) {
    const size_t idx = base + (size_t)t * MDIM;
    const ushort4 rv = *(const ushort4*)&r[idx];
    const ushort4 lv = *(const ushort4*)&L[idx];
    const ushort4 ov = *(const ushort4*)&og[idx];
    p0 *= bf2f(rv.x); p1 *= bf2f(rv.y); p2 *= bf2f(rv.z); p3 *= bf2f(rv.w);
    const float a0 = fmaf(p0, ci.x, bf2f(lv.x));
    const float a1 = fmaf(p1, ci.y, bf2f(lv.y));
    const float a2 = fmaf(p2, ci.z, bf2f(lv.z));
    const float a3 = fmaf(p3, ci.w, bf2f(lv.w));
    ushort4 o;
    o.x = f2bf(a0 / (1.0f + fabsf(a0)) * bf2f(ov.x));
    o.y = f2bf(a1 / (1.0f + fabsf(a1)) * bf2f(ov.y));
    o.z = f2bf(a2 / (1.0f + fabsf(a2)) * bf2f(ov.z));
    o.w = f2bf(a3 / (1.0f + fabsf(a3)) * bf2f(ov.w));
    *(ushort4*)&s[idx] = o;
  }
}

// ---------------- launch ----------------
extern "C" void kernel_launch(void* const* d_in, const int* in_sizes, int n_in,
                              void* d_out, int out_size, void* d_ws, size_t ws_size,
                              hipStream_t stream)
{
  const float* x        = (const float*)d_in[0];
  const float* mem      = (const float*)d_in[1];
  const float* norm_w   = (const float*)d_in[2];
  const float* wr_w     = (const float*)d_in[3];
  const float* wr_b     = (const float*)d_in[4];
  const float* wi_w     = (const float*)d_in[5];
  const float* wig_w    = (const float*)d_in[6];
  const float* wig_b    = (const float*)d_in[7];
  const float* wog_w    = (const float*)d_in[8];
  const float* wog_b    = (const float*)d_in[9];
  const float* wo_w     = (const float*)d_in[10];
  const float* ffnorm_w = (const float*)d_in[11];
  const float* ffn_wi_w = (const float*)d_in[12];
  const float* ffn_wg_w = (const float*)d_in[13];
  const float* ffn_wg_b = (const float*)d_in[14];
  const float* ffn_wo_w = (const float*)d_in[15];
  float* outF = (float*)d_out;

  // d_out scratch (dead until final GEMM / passB):
  ushort* xgL  = (ushort*)d_out;                        // [0,32MB): xg -> L
  ushort* wbf  = (ushort*)((char*)d_out + 33554432ULL); // [32,46MB): 7M bf16 W
  float*  cL   = (float*)((char*)d_out + 48234496ULL);  // [46,50MB)
  float*  cP   = (float*)((char*)d_out + 52428800ULL);  // [50,54MB)
  float*  cIn  = (float*)((char*)d_out + 56623104ULL);  // [54,58MB)
  float*  memoutF = outF + 16777216;                    // mem_out fp32

  // ws (~97MB):
  char* ws = (char*)d_ws;
  ushort* y   = (ushort*)(ws);                 // 32MB bf16: y -> s -> gf/ff
  ushort* r   = (ushort*)(ws + 33554432ULL);   // 32MB bf16: r -> z
  ushort* og  = (ushort*)(ws + 67108864ULL);   // 32MB bf16: og -> x1
  ushort* fwo_bf = (ushort*)(ws + 100663296ULL); // 2MB bf16 ffn_wo
  ushort* s   = y;
  ushort* x1  = og;
  ushort* z   = r;
  ushort* gf  = y;                             // ffn ff

  cvt_weights<<<dim3(1024, 8), 256, 0, stream>>>(
      wr_w, wog_w, wig_w, wi_w, ffn_wg_w, ffn_wi_w, wo_w, ffn_wo_w,
      wbf, fwo_bf);

  // sqrll branch: one dispatch -> r, og, xg
  rmsnorm_k<true><<<R_ROWS / 2, 256, 0, stream>>>(x, norm_w, y);
  gemm8<6><<<dim3(64, 16), 512, 0, stream>>>(
      y, wbf, wr_b, nullptr, nullptr, r, nullptr, wog_b, wig_b, og, xgL);
  linrec_passA<<<1024, 256, 0, stream>>>(xgL, r, cL, cP);
  linrec_passB<<<64, 64, 0, stream>>>(cL, cP, mem, cIn, memoutF);
  linrec_passC<<<1024, 256, 0, stream>>>(xgL, r, og, cIn, s);
  gemm8<1><<<dim3(64, 4), 512, 0, stream>>>(
      s, wbf + 4194304, nullptr, x, nullptr, x1, nullptr,
      nullptr, nullptr, nullptr, nullptr);
  // ffn branch: gated in one dispatch -> ff
  rmsnorm_k<false><<<R_ROWS / 2, 256, 0, stream>>>(x1, ffnorm_w, z);
  gemm8<5><<<dim3(64, 8), 512, 0, stream>>>(
      z, wbf + 5242880, ffn_wg_b, nullptr, nullptr, gf, nullptr,
      nullptr, nullptr, nullptr, nullptr);
  gemm8<3><<<dim3(64, 4), 512, 0, stream>>>(
      gf, fwo_bf, nullptr, nullptr, x1, nullptr, outF,
      nullptr, nullptr, nullptr, nullptr);
}